// Round 1
// baseline (31346.024 us; speedup 1.0000x reference)
//
#include <hip/hip_runtime.h>

#define HWD  96
#define NPIX (HWD*HWD)   // 9216
#define CIN  64
#define COUT 64
#define CTOT 128         // CIN + COUT
#define BB   4
#define TT   8
#define WSTR (CTOT*9)    // weight stride per output channel (1152)

__device__ __forceinline__ float sigmoid_(float v) {
    // robust: v->-inf => exp->inf => 0 ; v->+inf => exp->0 => 1
    return 1.0f / (1.0f + __expf(-v));
}
__device__ __forceinline__ float tanh_(float v) {
    float e = __expf(2.0f * fabsf(v));     // e in [1, inf]
    float t = 1.0f - 2.0f / (e + 1.0f);    // in [0,1), robust at inf
    return copysignf(t, v);
}

// ---------------------------------------------------------------------------
// Kernel A: r,z gates. Writes z into out[slice t] (scratch; overwritten by
// kernel B with h_new) and r*h_prev into ws.
// ---------------------------------------------------------------------------
__global__ __launch_bounds__(256) void gates_kernel(
    const float* __restrict__ x,      // [B,T,CIN,NPIX]
    const float* __restrict__ wr,     // [COUT,CTOT,3,3]
    const float* __restrict__ br,     // [COUT]
    const float* __restrict__ wz,
    const float* __restrict__ bz,
    float* __restrict__ out,          // [B,T,COUT,NPIX]
    float* __restrict__ rh,           // [B,COUT,NPIX]  (workspace)
    int t)
{
    const int p  = blockIdx.x * 256 + threadIdx.x;
    const int b  = blockIdx.y;
    const int yy = p / HWD;
    const int xx = p - yy * HWD;

    float racc[COUT], zacc[COUT];
#pragma unroll
    for (int oc = 0; oc < COUT; ++oc) { racc[oc] = br[oc]; zacc[oc] = bz[oc]; }

    // 9-tap offsets: clamped address + validity mask (branchless loads)
    int offc[9]; bool ok[9];
#pragma unroll
    for (int ky = 0; ky < 3; ++ky)
#pragma unroll
        for (int kx = 0; kx < 3; ++kx) {
            int yt = yy + ky - 1, xt = xx + kx - 1;
            int k = ky * 3 + kx;
            ok[k] = ((unsigned)yt < HWD) && ((unsigned)xt < HWD);
            int yc = min(max(yt, 0), HWD - 1);
            int xc = min(max(xt, 0), HWD - 1);
            offc[k] = yc * HWD + xc;
        }

    const float* xb = x + ((size_t)(b * TT + t) * CIN) * NPIX;
    for (int ic = 0; ic < CIN; ++ic) {
        float v[9];
#pragma unroll
        for (int k = 0; k < 9; ++k) {
            float vv = xb[ic * NPIX + offc[k]];
            v[k] = ok[k] ? vv : 0.0f;
        }
        const float* wrp = wr + ic * 9;   // + oc*WSTR + k (wave-uniform)
        const float* wzp = wz + ic * 9;
#pragma unroll
        for (int oc = 0; oc < COUT; ++oc) {
#pragma unroll
            for (int k = 0; k < 9; ++k) {
                racc[oc] = fmaf(v[k], wrp[oc * WSTR + k], racc[oc]);
                zacc[oc] = fmaf(v[k], wzp[oc * WSTR + k], zacc[oc]);
            }
        }
    }

    const float* hb = out + ((size_t)(b * TT + (t - 1)) * COUT) * NPIX; // valid iff t>0
    if (t > 0) {
        for (int ic = 0; ic < COUT; ++ic) {
            float v[9];
#pragma unroll
            for (int k = 0; k < 9; ++k) {
                float vv = hb[ic * NPIX + offc[k]];
                v[k] = ok[k] ? vv : 0.0f;
            }
            const float* wrp = wr + (CIN + ic) * 9;
            const float* wzp = wz + (CIN + ic) * 9;
#pragma unroll
            for (int oc = 0; oc < COUT; ++oc) {
#pragma unroll
                for (int k = 0; k < 9; ++k) {
                    racc[oc] = fmaf(v[k], wrp[oc * WSTR + k], racc[oc]);
                    zacc[oc] = fmaf(v[k], wzp[oc * WSTR + k], zacc[oc]);
                }
            }
        }
    }

    float* zout = out + ((size_t)(b * TT + t) * COUT) * NPIX;
    float* rhp  = rh + ((size_t)b * COUT) * NPIX;
#pragma unroll
    for (int oc = 0; oc < COUT; ++oc) {
        float r = sigmoid_(racc[oc]);
        float z = sigmoid_(zacc[oc]);
        zout[oc * NPIX + p] = z;
        float hv = (t > 0) ? hb[oc * NPIX + p] : 0.0f;
        rhp[oc * NPIX + p] = r * hv;
    }
}

// ---------------------------------------------------------------------------
// Kernel B: h_tilde conv over concat(x, r*h), then GRU update.
// Reads z from out[slice t], overwrites with h_new (same thread, same addr).
// ---------------------------------------------------------------------------
__global__ __launch_bounds__(256) void cand_kernel(
    const float* __restrict__ x,      // [B,T,CIN,NPIX]
    const float* __restrict__ rh,     // [B,COUT,NPIX]
    const float* __restrict__ wh,
    const float* __restrict__ bh,
    float* __restrict__ out,          // [B,T,COUT,NPIX]
    int t)
{
    const int p  = blockIdx.x * 256 + threadIdx.x;
    const int b  = blockIdx.y;
    const int yy = p / HWD;
    const int xx = p - yy * HWD;

    float hacc[COUT];
#pragma unroll
    for (int oc = 0; oc < COUT; ++oc) hacc[oc] = bh[oc];

    int offc[9]; bool ok[9];
#pragma unroll
    for (int ky = 0; ky < 3; ++ky)
#pragma unroll
        for (int kx = 0; kx < 3; ++kx) {
            int yt = yy + ky - 1, xt = xx + kx - 1;
            int k = ky * 3 + kx;
            ok[k] = ((unsigned)yt < HWD) && ((unsigned)xt < HWD);
            int yc = min(max(yt, 0), HWD - 1);
            int xc = min(max(xt, 0), HWD - 1);
            offc[k] = yc * HWD + xc;
        }

    const float* xb  = x + ((size_t)(b * TT + t) * CIN) * NPIX;
    const float* rhp = rh + ((size_t)b * COUT) * NPIX;

    for (int ic = 0; ic < CIN; ++ic) {
        float v[9];
#pragma unroll
        for (int k = 0; k < 9; ++k) {
            float vv = xb[ic * NPIX + offc[k]];
            v[k] = ok[k] ? vv : 0.0f;
        }
        const float* whp = wh + ic * 9;
#pragma unroll
        for (int oc = 0; oc < COUT; ++oc) {
#pragma unroll
            for (int k = 0; k < 9; ++k)
                hacc[oc] = fmaf(v[k], whp[oc * WSTR + k], hacc[oc]);
        }
    }
    for (int ic = 0; ic < COUT; ++ic) {
        float v[9];
#pragma unroll
        for (int k = 0; k < 9; ++k) {
            float vv = rhp[ic * NPIX + offc[k]];
            v[k] = ok[k] ? vv : 0.0f;
        }
        const float* whp = wh + (CIN + ic) * 9;
#pragma unroll
        for (int oc = 0; oc < COUT; ++oc) {
#pragma unroll
            for (int k = 0; k < 9; ++k)
                hacc[oc] = fmaf(v[k], whp[oc * WSTR + k], hacc[oc]);
        }
    }

    float* o = out + ((size_t)(b * TT + t) * COUT) * NPIX;
    const float* hb = out + ((size_t)(b * TT + (t - 1)) * COUT) * NPIX;
#pragma unroll
    for (int oc = 0; oc < COUT; ++oc) {
        float z  = o[oc * NPIX + p];
        float hv = (t > 0) ? hb[oc * NPIX + p] : 0.0f;
        float ht = tanh_(hacc[oc]);
        // (1-z)*h + z*ht  ==  h + z*(ht - h)
        o[oc * NPIX + p] = fmaf(z, ht - hv, hv);
    }
}

extern "C" void kernel_launch(void* const* d_in, const int* in_sizes, int n_in,
                              void* d_out, int out_size, void* d_ws, size_t ws_size,
                              hipStream_t stream) {
    const float* x  = (const float*)d_in[0];
    const float* wr = (const float*)d_in[1];
    const float* br = (const float*)d_in[2];
    const float* wz = (const float*)d_in[3];
    const float* bz = (const float*)d_in[4];
    const float* wh = (const float*)d_in[5];
    const float* bh = (const float*)d_in[6];
    float* out = (float*)d_out;
    float* rh  = (float*)d_ws;   // [B, COUT, NPIX] floats = 9.44 MB

    dim3 grid(NPIX / 256, BB);
    for (int t = 0; t < TT; ++t) {
        gates_kernel<<<grid, 256, 0, stream>>>(x, wr, br, wz, bz, out, rh, t);
        cand_kernel<<<grid, 256, 0, stream>>>(x, rh, wh, bh, out, t);
    }
}

// Round 2
// 4366.674 us; speedup vs baseline: 7.1785x; 7.1785x over previous
//
#include <hip/hip_runtime.h>

#define HWD  96
#define NPIX (HWD*HWD)   // 9216
#define CIN  64
#define COUT 64
#define CTOT 128         // CIN + COUT
#define BB   4
#define TT   8
#define WSTR (CTOT*9)    // weight stride per output channel (1152)
#define OCT  16          // output channels per thread (register tile)

__device__ __forceinline__ float sigmoid_(float v) {
    return 1.0f / (1.0f + __expf(-v));
}
__device__ __forceinline__ float tanh_(float v) {
    float e = __expf(2.0f * fabsf(v));
    float t = 1.0f - 2.0f / (e + 1.0f);
    return copysignf(t, v);
}

__device__ __forceinline__ void make_taps(int p, int* offc, bool* ok) {
    const int yy = p / HWD;
    const int xx = p - yy * HWD;
#pragma unroll
    for (int ky = 0; ky < 3; ++ky)
#pragma unroll
        for (int kx = 0; kx < 3; ++kx) {
            int yt = yy + ky - 1, xt = xx + kx - 1;
            int k = ky * 3 + kx;
            ok[k] = ((unsigned)yt < HWD) && ((unsigned)xt < HWD);
            int yc = min(max(yt, 0), HWD - 1);
            int xc = min(max(xt, 0), HWD - 1);
            offc[k] = yc * HWD + xc;
        }
}

// conv partial: acc[OCT] += sum_ic sum_k in[ic,p+off(k)] * w[oc0+j, icbase+ic, k]
__device__ __forceinline__ void conv_accum(
    float* acc, const float* __restrict__ src, const float* __restrict__ w,
    int oc0, int icbase, int nic, const int* offc, const bool* ok)
{
#pragma unroll 1
    for (int ic = 0; ic < nic; ++ic) {
        float v[9];
#pragma unroll
        for (int k = 0; k < 9; ++k) {
            float vv = src[ic * NPIX + offc[k]];
            v[k] = ok[k] ? vv : 0.0f;
        }
        const float* wp = w + (size_t)oc0 * WSTR + (size_t)(icbase + ic) * 9;
#pragma unroll
        for (int j = 0; j < OCT; ++j)
#pragma unroll
            for (int k = 0; k < 9; ++k)
                acc[j] = fmaf(v[k], wp[(size_t)j * WSTR + k], acc[j]);
    }
}

// ---------------------------------------------------------------------------
// Kernel A: r,z gates. Channel-groups 0..3 -> r (writes r*h_prev to ws),
// groups 4..7 -> z (writes z into out slice t as scratch).
// ---------------------------------------------------------------------------
__global__ __launch_bounds__(256) void gates_kernel(
    const float* __restrict__ x,      // [B,T,CIN,NPIX]
    const float* __restrict__ wr, const float* __restrict__ br,
    const float* __restrict__ wz, const float* __restrict__ bz,
    float* __restrict__ out,          // [B,T,COUT,NPIX]
    float* __restrict__ rh,           // [B,COUT,NPIX]  (workspace)
    int t)
{
    const int p  = blockIdx.x * 256 + threadIdx.x;
    const int b  = blockIdx.y;
    const int g  = blockIdx.z;                 // 0..7
    const bool is_r = (g < 4);
    const int oc0 = (g & 3) * OCT;

    const float* w    = is_r ? wr : wz;
    const float* bias = is_r ? br : bz;

    float acc[OCT];
#pragma unroll
    for (int j = 0; j < OCT; ++j) acc[j] = bias[oc0 + j];

    int offc[9]; bool ok[9];
    make_taps(p, offc, ok);

    const float* xb = x + ((size_t)(b * TT + t) * CIN) * NPIX;
    conv_accum(acc, xb, w, oc0, 0, CIN, offc, ok);

    const float* hb = out + ((size_t)(b * TT + (t - 1)) * COUT) * NPIX;
    if (t > 0)
        conv_accum(acc, hb, w, oc0, CIN, COUT, offc, ok);

    if (is_r) {
        float* rhp = rh + ((size_t)b * COUT) * NPIX;
#pragma unroll
        for (int j = 0; j < OCT; ++j) {
            float hv = (t > 0) ? hb[(oc0 + j) * NPIX + p] : 0.0f;
            rhp[(oc0 + j) * NPIX + p] = sigmoid_(acc[j]) * hv;
        }
    } else {
        float* zout = out + ((size_t)(b * TT + t) * COUT) * NPIX;
#pragma unroll
        for (int j = 0; j < OCT; ++j)
            zout[(oc0 + j) * NPIX + p] = sigmoid_(acc[j]);
    }
}

// ---------------------------------------------------------------------------
// Kernel B: h_tilde conv over concat(x, r*h), then GRU update.
// ---------------------------------------------------------------------------
__global__ __launch_bounds__(256) void cand_kernel(
    const float* __restrict__ x,      // [B,T,CIN,NPIX]
    const float* __restrict__ rh,     // [B,COUT,NPIX]
    const float* __restrict__ wh, const float* __restrict__ bh,
    float* __restrict__ out,          // [B,T,COUT,NPIX]
    int t)
{
    const int p  = blockIdx.x * 256 + threadIdx.x;
    const int b  = blockIdx.y;
    const int oc0 = blockIdx.z * OCT;          // 0..3 groups

    float acc[OCT];
#pragma unroll
    for (int j = 0; j < OCT; ++j) acc[j] = bh[oc0 + j];

    int offc[9]; bool ok[9];
    make_taps(p, offc, ok);

    const float* xb  = x + ((size_t)(b * TT + t) * CIN) * NPIX;
    const float* rhp = rh + ((size_t)b * COUT) * NPIX;

    conv_accum(acc, xb,  wh, oc0, 0,   CIN,  offc, ok);
    conv_accum(acc, rhp, wh, oc0, CIN, COUT, offc, ok);

    float* o = out + ((size_t)(b * TT + t) * COUT) * NPIX;
    const float* hb = out + ((size_t)(b * TT + (t - 1)) * COUT) * NPIX;
#pragma unroll
    for (int j = 0; j < OCT; ++j) {
        float z  = o[(oc0 + j) * NPIX + p];
        float hv = (t > 0) ? hb[(oc0 + j) * NPIX + p] : 0.0f;
        float ht = tanh_(acc[j]);
        o[(oc0 + j) * NPIX + p] = fmaf(z, ht - hv, hv);   // h + z*(ht-h)
    }
}

extern "C" void kernel_launch(void* const* d_in, const int* in_sizes, int n_in,
                              void* d_out, int out_size, void* d_ws, size_t ws_size,
                              hipStream_t stream) {
    const float* x  = (const float*)d_in[0];
    const float* wr = (const float*)d_in[1];
    const float* br = (const float*)d_in[2];
    const float* wz = (const float*)d_in[3];
    const float* bz = (const float*)d_in[4];
    const float* wh = (const float*)d_in[5];
    const float* bh = (const float*)d_in[6];
    float* out = (float*)d_out;
    float* rh  = (float*)d_ws;   // [B, COUT, NPIX] floats = 9.44 MB

    dim3 ggrid(NPIX / 256, BB, 8);
    dim3 cgrid(NPIX / 256, BB, 4);
    for (int t = 0; t < TT; ++t) {
        gates_kernel<<<ggrid, 256, 0, stream>>>(x, wr, br, wz, bz, out, rh, t);
        cand_kernel<<<cgrid, 256, 0, stream>>>(x, rh, wh, bh, out, t);
    }
}

// Round 3
// 862.134 us; speedup vs baseline: 36.3586x; 5.0650x over previous
//
#include <hip/hip_runtime.h>

#define HWD  96
#define NPIX (HWD*HWD)   // 9216
#define CIN  64
#define COUT 64
#define CTOT 128
#define BB   4
#define TT   8
#define WSTR (CTOT*9)    // weight stride per oc in source layout

typedef short bf16x8 __attribute__((ext_vector_type(8)));
typedef float f32x4  __attribute__((ext_vector_type(4)));

__device__ __forceinline__ float sigmoid_(float v){ return 1.0f/(1.0f+__expf(-v)); }
__device__ __forceinline__ float tanh_(float v){
    float e = __expf(2.0f*fabsf(v));
    float t = 1.0f - 2.0f/(e+1.0f);
    return copysignf(t, v);
}
__device__ __forceinline__ short f2bf(float f){      // RNE float->bf16 bits
    unsigned u = __float_as_uint(f);
    u += 0x7fffu + ((u>>16)&1u);
    return (short)(u>>16);
}

// ---------------------------------------------------------------------------
// Transpose-convert one timestep of x: [b][ic][px] fp32 -> [b][px][ic] bf16
// ---------------------------------------------------------------------------
__global__ __launch_bounds__(256) void convert_x(const float* __restrict__ x,
                                                 short* __restrict__ xt, int t){
    __shared__ float tile[64][65];
    const int b   = blockIdx.y;
    const int px0 = blockIdx.x * 64;
    const float* src = x + ((size_t)(b*TT + t)*CIN)*NPIX;
    short* dst = xt + ((size_t)b*NPIX)*CIN;
    const int tid = threadIdx.x;
#pragma unroll
    for (int i = 0; i < 16; ++i){
        int ic = i*4 + (tid>>6);
        int pl = tid & 63;
        tile[ic][pl] = src[(size_t)ic*NPIX + px0 + pl];
    }
    __syncthreads();
#pragma unroll
    for (int i = 0; i < 16; ++i){
        int ic = tid & 63;
        int pl = i*4 + (tid>>6);
        dst[(size_t)(px0+pl)*CIN + ic] = f2bf(tile[ic][pl]);
    }
}

// ---------------------------------------------------------------------------
// Pre-shuffle weights into MFMA A-fragment order:
// wfrag[c][tap][kc][mt][lane][8]  where element = W_c[oc=mt*16+(lane&15)]
//   [ct=kc*32+(lane>>4)*8+j][tap].  Also zero-fills the border pad.
// ---------------------------------------------------------------------------
__global__ __launch_bounds__(256) void convert_w(const float* __restrict__ wr,
    const float* __restrict__ wz, const float* __restrict__ wh,
    short* __restrict__ wfrag, short* __restrict__ zpad){
    const int g = blockIdx.x*256 + threadIdx.x;      // 0 .. 27647
    if (g < 128) zpad[g] = 0;
    const int lane = g & 63, rest = g >> 6;          // rest: 0..431
    const int mt = rest & 3, kc = (rest>>2)&3, rem = rest>>4;
    const int tap = rem % 9, c = rem / 9;
    const float* wsrc = (c==0) ? wr : (c==1) ? wz : wh;
    const int oc  = mt*16 + (lane&15);
    const int ctb = kc*32 + (lane>>4)*8;
    bf16x8 v;
#pragma unroll
    for (int j=0;j<8;++j)
        v[j] = f2bf(wsrc[(size_t)oc*WSTR + (size_t)(ctb+j)*9 + tap]);
    *(bf16x8*)(wfrag + (size_t)g*8) = v;
}

// ---------------------------------------------------------------------------
// Gates: r,z convs via MFMA implicit GEMM. Writes z (fp32) into out slice t
// (scratch) and r*h_prev (bf16, [px][oc]) into rht.
// ---------------------------------------------------------------------------
__global__ __launch_bounds__(256) void gates_mfma(
    const short* __restrict__ xt, const short* __restrict__ ht,
    const short* __restrict__ wfrag, const short* __restrict__ zpad,
    const float* __restrict__ br, const float* __restrict__ bz,
    float* __restrict__ out, short* __restrict__ rht, int t)
{
    const int lane = threadIdx.x & 63;
    const int wave = threadIdx.x >> 6;
    const int quad = lane >> 4;
    const int col  = lane & 15;
    const int b = blockIdx.y;
    const int n_base = blockIdx.x*128 + wave*32;

    int px[2], xx[2], yy[2];
#pragma unroll
    for (int nt=0; nt<2; ++nt){
        px[nt] = n_base + nt*16 + col;
        yy[nt] = px[nt]/HWD;
        xx[nt] = px[nt] - yy[nt]*HWD;
    }

    f32x4 acc[2][4][2];
#pragma unroll
    for(int c=0;c<2;++c)
#pragma unroll
    for(int mt=0;mt<4;++mt)
#pragma unroll
    for(int nt=0;nt<2;++nt)
        acc[c][mt][nt] = f32x4{0.f,0.f,0.f,0.f};

    const short* xs = xt + ((size_t)b*NPIX)*CIN;
    const short* hs = ht + ((size_t)b*NPIX)*COUT;
    const int nparts = (t>0) ? 2 : 1;

    for (int part=0; part<nparts; ++part){
        const short* src = part ? hs : xs;
        for (int tap=0; tap<9; ++tap){
            const int ky = tap/3, kx = tap-3*ky;
            const int off = (ky-1)*HWD + (kx-1);
            const short* bp[2];
#pragma unroll
            for (int nt=0;nt<2;++nt){
                bool v = ((unsigned)(yy[nt]+ky-1) < HWD) && ((unsigned)(xx[nt]+kx-1) < HWD);
                bp[nt] = v ? (src + (size_t)(px[nt]+off)*CIN) : zpad;
            }
#pragma unroll
            for (int kcl=0; kcl<2; ++kcl){
                const int kc = part*2 + kcl;
                bf16x8 bfr[2];
#pragma unroll
                for (int nt=0;nt<2;++nt)
                    bfr[nt] = *(const bf16x8*)(bp[nt] + kcl*32 + quad*8);
#pragma unroll
                for (int c=0;c<2;++c){
                    const short* wc = wfrag + (size_t)(((c*9+tap)*4 + kc)*4)*64*8;
#pragma unroll
                    for (int mt=0;mt<4;++mt){
                        bf16x8 a = *(const bf16x8*)(wc + (size_t)(mt*64+lane)*8);
#pragma unroll
                        for (int nt=0;nt<2;++nt)
                            acc[c][mt][nt] = __builtin_amdgcn_mfma_f32_16x16x32_bf16(
                                a, bfr[nt], acc[c][mt][nt], 0, 0, 0);
                    }
                }
            }
        }
    }

    float* zout = out + ((size_t)(b*TT+t)*COUT)*NPIX;
    const float* hprev = out + ((size_t)(b*TT+t-1)*COUT)*NPIX;   // only deref if t>0
    short* rhs = rht + ((size_t)b*NPIX)*COUT;
#pragma unroll
    for (int mt=0; mt<4; ++mt){
        const int ocb = mt*16 + quad*4;
#pragma unroll
        for (int nt=0; nt<2; ++nt){
            const int p = px[nt];
            short rh4[4];
#pragma unroll
            for (int reg=0; reg<4; ++reg){
                const int oc = ocb + reg;
                float z = sigmoid_(acc[1][mt][nt][reg] + bz[oc]);
                zout[(size_t)oc*NPIX + p] = z;
                float hv = (t>0) ? hprev[(size_t)oc*NPIX + p] : 0.0f;
                float r  = sigmoid_(acc[0][mt][nt][reg] + br[oc]);
                rh4[reg] = f2bf(r*hv);
            }
            *(short4*)(rhs + (size_t)p*COUT + ocb) =
                make_short4(rh4[0], rh4[1], rh4[2], rh4[3]);
        }
    }
}

// ---------------------------------------------------------------------------
// Candidate: h_tilde conv over [x, r*h] via MFMA, then GRU update.
// Reads z (fp32) from out slice t, overwrites with h_new; emits h_new bf16
// ([px][oc]) into ht for the next step.
// ---------------------------------------------------------------------------
__global__ __launch_bounds__(256) void cand_mfma(
    const short* __restrict__ xt, const short* __restrict__ rht,
    const short* __restrict__ wfrag, const short* __restrict__ zpad,
    const float* __restrict__ bh,
    float* __restrict__ out, short* __restrict__ ht, int t)
{
    const int lane = threadIdx.x & 63;
    const int wave = threadIdx.x >> 6;
    const int quad = lane >> 4;
    const int col  = lane & 15;
    const int b = blockIdx.y;
    const int n_base = blockIdx.x*128 + wave*32;

    int px[2], xx[2], yy[2];
#pragma unroll
    for (int nt=0; nt<2; ++nt){
        px[nt] = n_base + nt*16 + col;
        yy[nt] = px[nt]/HWD;
        xx[nt] = px[nt] - yy[nt]*HWD;
    }

    f32x4 acc[4][2];
#pragma unroll
    for(int mt=0;mt<4;++mt)
#pragma unroll
    for(int nt=0;nt<2;++nt)
        acc[mt][nt] = f32x4{0.f,0.f,0.f,0.f};

    const short* xs = xt + ((size_t)b*NPIX)*CIN;
    const short* rs = rht + ((size_t)b*NPIX)*COUT;
    const int nparts = (t>0) ? 2 : 1;

    for (int part=0; part<nparts; ++part){
        const short* src = part ? rs : xs;
        for (int tap=0; tap<9; ++tap){
            const int ky = tap/3, kx = tap-3*ky;
            const int off = (ky-1)*HWD + (kx-1);
            const short* bp[2];
#pragma unroll
            for (int nt=0;nt<2;++nt){
                bool v = ((unsigned)(yy[nt]+ky-1) < HWD) && ((unsigned)(xx[nt]+kx-1) < HWD);
                bp[nt] = v ? (src + (size_t)(px[nt]+off)*CIN) : zpad;
            }
#pragma unroll
            for (int kcl=0; kcl<2; ++kcl){
                const int kc = part*2 + kcl;
                bf16x8 bfr[2];
#pragma unroll
                for (int nt=0;nt<2;++nt)
                    bfr[nt] = *(const bf16x8*)(bp[nt] + kcl*32 + quad*8);
                const short* wc = wfrag + (size_t)(((2*9+tap)*4 + kc)*4)*64*8;
#pragma unroll
                for (int mt=0;mt<4;++mt){
                    bf16x8 a = *(const bf16x8*)(wc + (size_t)(mt*64+lane)*8);
#pragma unroll
                    for (int nt=0;nt<2;++nt)
                        acc[mt][nt] = __builtin_amdgcn_mfma_f32_16x16x32_bf16(
                            a, bfr[nt], acc[mt][nt], 0, 0, 0);
                }
            }
        }
    }

    float* o = out + ((size_t)(b*TT+t)*COUT)*NPIX;
    const float* hprev = out + ((size_t)(b*TT+t-1)*COUT)*NPIX;   // only deref if t>0
    short* hts = ht + ((size_t)b*NPIX)*COUT;
#pragma unroll
    for (int mt=0; mt<4; ++mt){
        const int ocb = mt*16 + quad*4;
#pragma unroll
        for (int nt=0; nt<2; ++nt){
            const int p = px[nt];
            short h4[4];
#pragma unroll
            for (int reg=0; reg<4; ++reg){
                const int oc = ocb + reg;
                float htl = tanh_(acc[mt][nt][reg] + bh[oc]);
                float z   = o[(size_t)oc*NPIX + p];
                float hv  = (t>0) ? hprev[(size_t)oc*NPIX + p] : 0.0f;
                float hn  = fmaf(z, htl - hv, hv);     // (1-z)h + z*htilde
                o[(size_t)oc*NPIX + p] = hn;
                h4[reg] = f2bf(hn);
            }
            *(short4*)(hts + (size_t)p*COUT + ocb) =
                make_short4(h4[0], h4[1], h4[2], h4[3]);
        }
    }
}

extern "C" void kernel_launch(void* const* d_in, const int* in_sizes, int n_in,
                              void* d_out, int out_size, void* d_ws, size_t ws_size,
                              hipStream_t stream) {
    const float* x  = (const float*)d_in[0];
    const float* wr = (const float*)d_in[1];
    const float* br = (const float*)d_in[2];
    const float* wz = (const float*)d_in[3];
    const float* bz = (const float*)d_in[4];
    const float* wh = (const float*)d_in[5];
    const float* bh = (const float*)d_in[6];
    float* out = (float*)d_out;

    // workspace layout (bf16 shorts): x_t | h_t | rh_t | wfrag | zpad  (~14.6 MB)
    short* xt  = (short*)d_ws;                               // [B][NPIX][CIN]
    short* htb = xt  + (size_t)BB*NPIX*CIN;                  // [B][NPIX][COUT]
    short* rht = htb + (size_t)BB*NPIX*COUT;                 // [B][NPIX][COUT]
    short* wf  = rht + (size_t)BB*NPIX*COUT;                 // 3*9*4*4*64*8
    short* zp  = wf  + (size_t)3*9*4*4*64*8;                 // 128 zeros

    convert_w<<<108, 256, 0, stream>>>(wr, wz, wh, wf, zp);

    dim3 cxgrid(NPIX/64, BB);
    dim3 ggrid(NPIX/128, BB);
    for (int t = 0; t < TT; ++t) {
        convert_x<<<cxgrid, 256, 0, stream>>>(x, xt, t);
        gates_mfma<<<ggrid, 256, 0, stream>>>(xt, htb, wf, zp, br, bz, out, rht, t);
        cand_mfma <<<ggrid, 256, 0, stream>>>(xt, rht, wf, zp, bh, out, htb, t);
    }
}

// Round 4
// 716.274 us; speedup vs baseline: 43.7626x; 1.2036x over previous
//
#include <hip/hip_runtime.h>
#include <hip/hip_fp16.h>

#define HWD  96
#define NPIX (HWD*HWD)   // 9216
#define CIN  64
#define COUT 64
#define CTOT 128
#define BB   4
#define TT   8
#define WSTR (CTOT*9)    // weight stride per oc in source layout

typedef short bf16x8 __attribute__((ext_vector_type(8)));
typedef float f32x4  __attribute__((ext_vector_type(4)));

__device__ __forceinline__ float sigmoid_(float v){ return 1.0f/(1.0f+__expf(-v)); }
__device__ __forceinline__ float tanh_(float v){
    float e = __expf(2.0f*fabsf(v));
    float t = 1.0f - 2.0f/(e+1.0f);
    return copysignf(t, v);
}
__device__ __forceinline__ short f2bf(float f){      // RNE float->bf16 bits
    unsigned u = __float_as_uint(f);
    u += 0x7fffu + ((u>>16)&1u);
    return (short)(u>>16);
}
__device__ __forceinline__ short f2h(float f){
    return (short)__half_as_ushort(__float2half(f));
}
__device__ __forceinline__ float h2f(short s){
    return __half2float(__ushort_as_half((unsigned short)s));
}

// ---------------------------------------------------------------------------
// Transpose-convert x: [bt][ic][px] fp32 -> [bt][px][ic] bf16, all timesteps.
// ---------------------------------------------------------------------------
__global__ __launch_bounds__(256) void convert_x_all(const float* __restrict__ x,
                                                     short* __restrict__ xt){
    __shared__ float tile[64][65];
    const int bt  = blockIdx.y;
    const int px0 = blockIdx.x * 64;
    const float* src = x + (size_t)bt*CIN*NPIX;
    short* dst = xt + (size_t)bt*NPIX*CIN;
    const int tid = threadIdx.x;
#pragma unroll
    for (int i = 0; i < 16; ++i){
        int ic = i*4 + (tid>>6);
        int pl = tid & 63;
        tile[ic][pl] = src[(size_t)ic*NPIX + px0 + pl];
    }
    __syncthreads();
#pragma unroll
    for (int i = 0; i < 16; ++i){
        int ic = tid & 63;
        int pl = i*4 + (tid>>6);
        dst[(size_t)(px0+pl)*CIN + ic] = f2bf(tile[ic][pl]);
    }
}

// per-timestep variant (fallback path)
__global__ __launch_bounds__(256) void convert_x(const float* __restrict__ x,
                                                 short* __restrict__ xt, int t){
    __shared__ float tile[64][65];
    const int b   = blockIdx.y;
    const int px0 = blockIdx.x * 64;
    const float* src = x + ((size_t)(b*TT + t)*CIN)*NPIX;
    short* dst = xt + ((size_t)b*NPIX)*CIN;
    const int tid = threadIdx.x;
#pragma unroll
    for (int i = 0; i < 16; ++i){
        int ic = i*4 + (tid>>6);
        int pl = tid & 63;
        tile[ic][pl] = src[(size_t)ic*NPIX + px0 + pl];
    }
    __syncthreads();
#pragma unroll
    for (int i = 0; i < 16; ++i){
        int ic = tid & 63;
        int pl = i*4 + (tid>>6);
        dst[(size_t)(px0+pl)*CIN + ic] = f2bf(tile[ic][pl]);
    }
}

// ---------------------------------------------------------------------------
// Weights -> MFMA A-fragment order: wfrag[c][tap][kc][mt][lane][8],
// element = W_c[oc=mt*16+(lane&15)][ct=kc*32+(lane>>4)*8+j][tap]. Zero pad too.
// ---------------------------------------------------------------------------
__global__ __launch_bounds__(256) void convert_w(const float* __restrict__ wr,
    const float* __restrict__ wz, const float* __restrict__ wh,
    short* __restrict__ wfrag, short* __restrict__ zpad){
    const int g = blockIdx.x*256 + threadIdx.x;      // 0 .. 27647
    if (g < 128) zpad[g] = 0;
    const int lane = g & 63, rest = g >> 6;
    const int mt = rest & 3, kc = (rest>>2)&3, rem = rest>>4;
    const int tap = rem % 9, c = rem / 9;
    const float* wsrc = (c==0) ? wr : (c==1) ? wz : wh;
    const int oc  = mt*16 + (lane&15);
    const int ctb = kc*32 + (lane>>4)*8;
    bf16x8 v;
#pragma unroll
    for (int j=0;j<8;++j)
        v[j] = f2bf(wsrc[(size_t)oc*WSTR + (size_t)(ctb+j)*9 + tap]);
    *(bf16x8*)(wfrag + (size_t)g*8) = v;
}

// ---------------------------------------------------------------------------
// Precompute Ux_c = conv(W_c[:, :64], x_t) for c in {r,z,h}, all (b,t).
// Output ux[c][bt][px][oc] fp16.  Grid (72, B*T, 3), massively parallel.
// ---------------------------------------------------------------------------
__global__ __launch_bounds__(256) void precompute_ux(
    const short* __restrict__ xt, const short* __restrict__ wfrag,
    const short* __restrict__ zpad, short* __restrict__ ux)
{
    const int lane = threadIdx.x & 63;
    const int wave = threadIdx.x >> 6;
    const int quad = lane >> 4, col = lane & 15;
    const int bt = blockIdx.y, c = blockIdx.z;
    const int n_base = blockIdx.x*128 + wave*32;

    int px[2], xx[2], yy[2];
#pragma unroll
    for (int nt=0; nt<2; ++nt){
        px[nt] = n_base + nt*16 + col;
        yy[nt] = px[nt]/HWD;
        xx[nt] = px[nt] - yy[nt]*HWD;
    }

    f32x4 acc[4][2];
#pragma unroll
    for (int mt=0;mt<4;++mt)
#pragma unroll
    for (int nt=0;nt<2;++nt) acc[mt][nt] = f32x4{0.f,0.f,0.f,0.f};

    const short* xs = xt + (size_t)bt*NPIX*CIN;
    for (int tap=0; tap<9; ++tap){
        const int ky = tap/3, kx = tap-3*ky;
        const int off = (ky-1)*HWD + (kx-1);
        const short* bp[2];
#pragma unroll
        for (int nt=0;nt<2;++nt){
            bool v = ((unsigned)(yy[nt]+ky-1) < HWD) && ((unsigned)(xx[nt]+kx-1) < HWD);
            bp[nt] = v ? (xs + (size_t)(px[nt]+off)*CIN) : zpad;
        }
#pragma unroll
        for (int kcl=0; kcl<2; ++kcl){
            bf16x8 bfr[2];
#pragma unroll
            for (int nt=0;nt<2;++nt)
                bfr[nt] = *(const bf16x8*)(bp[nt] + kcl*32 + quad*8);
            const short* wc = wfrag + (size_t)(((c*9+tap)*4 + kcl)*4)*64*8;
#pragma unroll
            for (int mt=0;mt<4;++mt){
                bf16x8 a = *(const bf16x8*)(wc + (size_t)(mt*64+lane)*8);
#pragma unroll
                for (int nt=0;nt<2;++nt)
                    acc[mt][nt] = __builtin_amdgcn_mfma_f32_16x16x32_bf16(
                        a, bfr[nt], acc[mt][nt], 0, 0, 0);
            }
        }
    }

    short* uxs = ux + ((size_t)c*(BB*TT) + bt)*NPIX*COUT;
#pragma unroll
    for (int mt=0; mt<4; ++mt){
        const int ocb = mt*16 + quad*4;
#pragma unroll
        for (int nt=0; nt<2; ++nt){
            short4 v;
            v.x = f2h(acc[mt][nt][0]); v.y = f2h(acc[mt][nt][1]);
            v.z = f2h(acc[mt][nt][2]); v.w = f2h(acc[mt][nt][3]);
            *(short4*)(uxs + (size_t)px[nt]*COUT + ocb) = v;
        }
    }
}

// ---------------------------------------------------------------------------
// Gates (sequential): only the h-part conv (K=64). blockIdx.z: 0=r, 1=z.
// acc += Ux (fp16 prologue load) + bias in epilogue.
// ---------------------------------------------------------------------------
__global__ __launch_bounds__(256) void gates2(
    const short* __restrict__ htb, const short* __restrict__ wfrag,
    const short* __restrict__ zpad, const short* __restrict__ ux,
    const float* __restrict__ br, const float* __restrict__ bz,
    float* __restrict__ out, short* __restrict__ rht, int t)
{
    const int lane = threadIdx.x & 63;
    const int wave = threadIdx.x >> 6;
    const int quad = lane >> 4, col = lane & 15;
    const int b = blockIdx.y, c = blockIdx.z;
    const int n_base = blockIdx.x*128 + wave*32;

    int px[2], xx[2], yy[2];
#pragma unroll
    for (int nt=0; nt<2; ++nt){
        px[nt] = n_base + nt*16 + col;
        yy[nt] = px[nt]/HWD;
        xx[nt] = px[nt] - yy[nt]*HWD;
    }

    // prologue: Ux loads (latency hidden behind MFMA loop)
    const short* uxs = ux + (((size_t)c*BB + b)*TT + t)*NPIX*COUT;
    short4 uxv[4][2];
#pragma unroll
    for (int mt=0; mt<4; ++mt)
#pragma unroll
    for (int nt=0; nt<2; ++nt)
        uxv[mt][nt] = *(const short4*)(uxs + (size_t)px[nt]*COUT + mt*16 + quad*4);

    f32x4 acc[4][2];
#pragma unroll
    for (int mt=0;mt<4;++mt)
#pragma unroll
    for (int nt=0;nt<2;++nt) acc[mt][nt] = f32x4{0.f,0.f,0.f,0.f};

    if (t > 0){
        const short* hs = htb + (size_t)b*NPIX*COUT;
        for (int tap=0; tap<9; ++tap){
            const int ky = tap/3, kx = tap-3*ky;
            const int off = (ky-1)*HWD + (kx-1);
            const short* bp[2];
#pragma unroll
            for (int nt=0;nt<2;++nt){
                bool v = ((unsigned)(yy[nt]+ky-1) < HWD) && ((unsigned)(xx[nt]+kx-1) < HWD);
                bp[nt] = v ? (hs + (size_t)(px[nt]+off)*COUT) : zpad;
            }
#pragma unroll
            for (int kcl=0; kcl<2; ++kcl){
                bf16x8 bfr[2];
#pragma unroll
                for (int nt=0;nt<2;++nt)
                    bfr[nt] = *(const bf16x8*)(bp[nt] + kcl*32 + quad*8);
                const short* wc = wfrag + (size_t)(((c*9+tap)*4 + 2+kcl)*4)*64*8;
#pragma unroll
                for (int mt=0;mt<4;++mt){
                    bf16x8 a = *(const bf16x8*)(wc + (size_t)(mt*64+lane)*8);
#pragma unroll
                    for (int nt=0;nt<2;++nt)
                        acc[mt][nt] = __builtin_amdgcn_mfma_f32_16x16x32_bf16(
                            a, bfr[nt], acc[mt][nt], 0, 0, 0);
                }
            }
        }
    }

    const float* hprev = out + ((size_t)(b*TT+t-1)*COUT)*NPIX;   // deref only if t>0
    if (c == 0){   // reset gate -> rh (bf16, [px][oc])
        short* rhs = rht + (size_t)b*NPIX*COUT;
#pragma unroll
        for (int mt=0; mt<4; ++mt){
            const int ocb = mt*16 + quad*4;
#pragma unroll
            for (int nt=0; nt<2; ++nt){
                const int p = px[nt];
                const short* uq = (const short*)&uxv[mt][nt];
                short rh4[4];
#pragma unroll
                for (int reg=0; reg<4; ++reg){
                    const int oc = ocb + reg;
                    float r  = sigmoid_(acc[mt][nt][reg] + h2f(uq[reg]) + br[oc]);
                    float hv = (t>0) ? hprev[(size_t)oc*NPIX + p] : 0.0f;
                    rh4[reg] = f2bf(r*hv);
                }
                *(short4*)(rhs + (size_t)p*COUT + ocb) =
                    make_short4(rh4[0], rh4[1], rh4[2], rh4[3]);
            }
        }
    } else {       // update gate -> z (fp32, scratch in out slice t)
        float* zout = out + ((size_t)(b*TT+t)*COUT)*NPIX;
#pragma unroll
        for (int mt=0; mt<4; ++mt){
            const int ocb = mt*16 + quad*4;
#pragma unroll
            for (int nt=0; nt<2; ++nt){
                const int p = px[nt];
                const short* uq = (const short*)&uxv[mt][nt];
#pragma unroll
                for (int reg=0; reg<4; ++reg){
                    const int oc = ocb + reg;
                    zout[(size_t)oc*NPIX + p] =
                        sigmoid_(acc[mt][nt][reg] + h2f(uq[reg]) + bz[oc]);
                }
            }
        }
    }
}

// ---------------------------------------------------------------------------
// Candidate (sequential): h-part conv over r*h (K=64) + GRU update.
// blockIdx.z = mh picks oc half (mt = mh*2 .. mh*2+1).
// ---------------------------------------------------------------------------
__global__ __launch_bounds__(256) void cand2(
    const short* __restrict__ rht, const short* __restrict__ wfrag,
    const short* __restrict__ zpad, const short* __restrict__ ux,
    const float* __restrict__ bh, float* __restrict__ out,
    short* __restrict__ htb, int t)
{
    const int lane = threadIdx.x & 63;
    const int wave = threadIdx.x >> 6;
    const int quad = lane >> 4, col = lane & 15;
    const int b = blockIdx.y, mh = blockIdx.z;
    const int n_base = blockIdx.x*128 + wave*32;

    int px[2], xx[2], yy[2];
#pragma unroll
    for (int nt=0; nt<2; ++nt){
        px[nt] = n_base + nt*16 + col;
        yy[nt] = px[nt]/HWD;
        xx[nt] = px[nt] - yy[nt]*HWD;
    }

    const short* uxs = ux + (((size_t)2*BB + b)*TT + t)*NPIX*COUT;
    short4 uxv[2][2];
#pragma unroll
    for (int mtl=0; mtl<2; ++mtl)
#pragma unroll
    for (int nt=0; nt<2; ++nt)
        uxv[mtl][nt] = *(const short4*)(uxs + (size_t)px[nt]*COUT + (mh*2+mtl)*16 + quad*4);

    f32x4 acc[2][2];
#pragma unroll
    for (int mtl=0;mtl<2;++mtl)
#pragma unroll
    for (int nt=0;nt<2;++nt) acc[mtl][nt] = f32x4{0.f,0.f,0.f,0.f};

    if (t > 0){
        const short* rs = rht + (size_t)b*NPIX*COUT;
        for (int tap=0; tap<9; ++tap){
            const int ky = tap/3, kx = tap-3*ky;
            const int off = (ky-1)*HWD + (kx-1);
            const short* bp[2];
#pragma unroll
            for (int nt=0;nt<2;++nt){
                bool v = ((unsigned)(yy[nt]+ky-1) < HWD) && ((unsigned)(xx[nt]+kx-1) < HWD);
                bp[nt] = v ? (rs + (size_t)(px[nt]+off)*COUT) : zpad;
            }
#pragma unroll
            for (int kcl=0; kcl<2; ++kcl){
                bf16x8 bfr[2];
#pragma unroll
                for (int nt=0;nt<2;++nt)
                    bfr[nt] = *(const bf16x8*)(bp[nt] + kcl*32 + quad*8);
                const short* wc = wfrag + (size_t)(((2*9+tap)*4 + 2+kcl)*4)*64*8;
#pragma unroll
                for (int mtl=0;mtl<2;++mtl){
                    const int mt = mh*2 + mtl;
                    bf16x8 a = *(const bf16x8*)(wc + (size_t)(mt*64+lane)*8);
#pragma unroll
                    for (int nt=0;nt<2;++nt)
                        acc[mtl][nt] = __builtin_amdgcn_mfma_f32_16x16x32_bf16(
                            a, bfr[nt], acc[mtl][nt], 0, 0, 0);
                }
            }
        }
    }

    float* o = out + ((size_t)(b*TT+t)*COUT)*NPIX;
    const float* hprev = out + ((size_t)(b*TT+t-1)*COUT)*NPIX;   // deref only if t>0
    short* hts = htb + (size_t)b*NPIX*COUT;
#pragma unroll
    for (int mtl=0; mtl<2; ++mtl){
        const int ocb = (mh*2+mtl)*16 + quad*4;
#pragma unroll
        for (int nt=0; nt<2; ++nt){
            const int p = px[nt];
            const short* uq = (const short*)&uxv[mtl][nt];
            short h4[4];
#pragma unroll
            for (int reg=0; reg<4; ++reg){
                const int oc = ocb + reg;
                float htl = tanh_(acc[mtl][nt][reg] + h2f(uq[reg]) + bh[oc]);
                float z   = o[(size_t)oc*NPIX + p];
                float hv  = (t>0) ? hprev[(size_t)oc*NPIX + p] : 0.0f;
                float hn  = fmaf(z, htl - hv, hv);
                o[(size_t)oc*NPIX + p] = hn;
                h4[reg] = f2bf(hn);
            }
            *(short4*)(hts + (size_t)p*COUT + ocb) =
                make_short4(h4[0], h4[1], h4[2], h4[3]);
        }
    }
}

// ===========================================================================
// Fallback kernels (R3 path, used only if workspace is too small for Ux)
// ===========================================================================
__global__ __launch_bounds__(256) void gates_mfma(
    const short* __restrict__ xt, const short* __restrict__ ht,
    const short* __restrict__ wfrag, const short* __restrict__ zpad,
    const float* __restrict__ br, const float* __restrict__ bz,
    float* __restrict__ out, short* __restrict__ rht, int t)
{
    const int lane = threadIdx.x & 63;
    const int wave = threadIdx.x >> 6;
    const int quad = lane >> 4, col = lane & 15;
    const int b = blockIdx.y;
    const int n_base = blockIdx.x*128 + wave*32;

    int px[2], xx[2], yy[2];
#pragma unroll
    for (int nt=0; nt<2; ++nt){
        px[nt] = n_base + nt*16 + col;
        yy[nt] = px[nt]/HWD;
        xx[nt] = px[nt] - yy[nt]*HWD;
    }
    f32x4 acc[2][4][2];
#pragma unroll
    for(int c=0;c<2;++c)
#pragma unroll
    for(int mt=0;mt<4;++mt)
#pragma unroll
    for(int nt=0;nt<2;++nt) acc[c][mt][nt] = f32x4{0.f,0.f,0.f,0.f};

    const short* xs = xt + ((size_t)b*NPIX)*CIN;
    const short* hs = ht + ((size_t)b*NPIX)*COUT;
    const int nparts = (t>0) ? 2 : 1;
    for (int part=0; part<nparts; ++part){
        const short* src = part ? hs : xs;
        for (int tap=0; tap<9; ++tap){
            const int ky = tap/3, kx = tap-3*ky;
            const int off = (ky-1)*HWD + (kx-1);
            const short* bp[2];
#pragma unroll
            for (int nt=0;nt<2;++nt){
                bool v = ((unsigned)(yy[nt]+ky-1) < HWD) && ((unsigned)(xx[nt]+kx-1) < HWD);
                bp[nt] = v ? (src + (size_t)(px[nt]+off)*CIN) : zpad;
            }
#pragma unroll
            for (int kcl=0; kcl<2; ++kcl){
                const int kc = part*2 + kcl;
                bf16x8 bfr[2];
#pragma unroll
                for (int nt=0;nt<2;++nt)
                    bfr[nt] = *(const bf16x8*)(bp[nt] + kcl*32 + quad*8);
#pragma unroll
                for (int c=0;c<2;++c){
                    const short* wc = wfrag + (size_t)(((c*9+tap)*4 + kc)*4)*64*8;
#pragma unroll
                    for (int mt=0;mt<4;++mt){
                        bf16x8 a = *(const bf16x8*)(wc + (size_t)(mt*64+lane)*8);
#pragma unroll
                        for (int nt=0;nt<2;++nt)
                            acc[c][mt][nt] = __builtin_amdgcn_mfma_f32_16x16x32_bf16(
                                a, bfr[nt], acc[c][mt][nt], 0, 0, 0);
                    }
                }
            }
        }
    }
    float* zout = out + ((size_t)(b*TT+t)*COUT)*NPIX;
    const float* hprev = out + ((size_t)(b*TT+t-1)*COUT)*NPIX;
    short* rhs = rht + ((size_t)b*NPIX)*COUT;
#pragma unroll
    for (int mt=0; mt<4; ++mt){
        const int ocb = mt*16 + quad*4;
#pragma unroll
        for (int nt=0; nt<2; ++nt){
            const int p = px[nt];
            short rh4[4];
#pragma unroll
            for (int reg=0; reg<4; ++reg){
                const int oc = ocb + reg;
                float z = sigmoid_(acc[1][mt][nt][reg] + bz[oc]);
                zout[(size_t)oc*NPIX + p] = z;
                float hv = (t>0) ? hprev[(size_t)oc*NPIX + p] : 0.0f;
                float r  = sigmoid_(acc[0][mt][nt][reg] + br[oc]);
                rh4[reg] = f2bf(r*hv);
            }
            *(short4*)(rhs + (size_t)p*COUT + ocb) =
                make_short4(rh4[0], rh4[1], rh4[2], rh4[3]);
        }
    }
}

__global__ __launch_bounds__(256) void cand_mfma(
    const short* __restrict__ xt, const short* __restrict__ rht,
    const short* __restrict__ wfrag, const short* __restrict__ zpad,
    const float* __restrict__ bh,
    float* __restrict__ out, short* __restrict__ ht, int t)
{
    const int lane = threadIdx.x & 63;
    const int wave = threadIdx.x >> 6;
    const int quad = lane >> 4, col = lane & 15;
    const int b = blockIdx.y;
    const int n_base = blockIdx.x*128 + wave*32;

    int px[2], xx[2], yy[2];
#pragma unroll
    for (int nt=0; nt<2; ++nt){
        px[nt] = n_base + nt*16 + col;
        yy[nt] = px[nt]/HWD;
        xx[nt] = px[nt] - yy[nt]*HWD;
    }
    f32x4 acc[4][2];
#pragma unroll
    for(int mt=0;mt<4;++mt)
#pragma unroll
    for(int nt=0;nt<2;++nt) acc[mt][nt] = f32x4{0.f,0.f,0.f,0.f};

    const short* xs = xt + ((size_t)b*NPIX)*CIN;
    const short* rs = rht + ((size_t)b*NPIX)*COUT;
    const int nparts = (t>0) ? 2 : 1;
    for (int part=0; part<nparts; ++part){
        const short* src = part ? rs : xs;
        for (int tap=0; tap<9; ++tap){
            const int ky = tap/3, kx = tap-3*ky;
            const int off = (ky-1)*HWD + (kx-1);
            const short* bp[2];
#pragma unroll
            for (int nt=0;nt<2;++nt){
                bool v = ((unsigned)(yy[nt]+ky-1) < HWD) && ((unsigned)(xx[nt]+kx-1) < HWD);
                bp[nt] = v ? (src + (size_t)(px[nt]+off)*CIN) : zpad;
            }
#pragma unroll
            for (int kcl=0; kcl<2; ++kcl){
                const int kc = part*2 + kcl;
                bf16x8 bfr[2];
#pragma unroll
                for (int nt=0;nt<2;++nt)
                    bfr[nt] = *(const bf16x8*)(bp[nt] + kcl*32 + quad*8);
                const short* wc = wfrag + (size_t)(((2*9+tap)*4 + kc)*4)*64*8;
#pragma unroll
                for (int mt=0;mt<4;++mt){
                    bf16x8 a = *(const bf16x8*)(wc + (size_t)(mt*64+lane)*8);
#pragma unroll
                    for (int nt=0;nt<2;++nt)
                        acc[mt][nt] = __builtin_amdgcn_mfma_f32_16x16x32_bf16(
                            a, bfr[nt], acc[mt][nt], 0, 0, 0);
                }
            }
        }
    }
    float* o = out + ((size_t)(b*TT+t)*COUT)*NPIX;
    const float* hprev = out + ((size_t)(b*TT+t-1)*COUT)*NPIX;
    short* hts = ht + ((size_t)b*NPIX)*COUT;
#pragma unroll
    for (int mt=0; mt<4; ++mt){
        const int ocb = mt*16 + quad*4;
#pragma unroll
        for (int nt=0; nt<2; ++nt){
            const int p = px[nt];
            short h4[4];
#pragma unroll
            for (int reg=0; reg<4; ++reg){
                const int oc = ocb + reg;
                float htl = tanh_(acc[mt][nt][reg] + bh[oc]);
                float z   = o[(size_t)oc*NPIX + p];
                float hv  = (t>0) ? hprev[(size_t)oc*NPIX + p] : 0.0f;
                float hn  = fmaf(z, htl - hv, hv);
                o[(size_t)oc*NPIX + p] = hn;
                h4[reg] = f2bf(hn);
            }
            *(short4*)(hts + (size_t)p*COUT + ocb) =
                make_short4(h4[0], h4[1], h4[2], h4[3]);
        }
    }
}

extern "C" void kernel_launch(void* const* d_in, const int* in_sizes, int n_in,
                              void* d_out, int out_size, void* d_ws, size_t ws_size,
                              hipStream_t stream) {
    const float* x  = (const float*)d_in[0];
    const float* wr = (const float*)d_in[1];
    const float* br = (const float*)d_in[2];
    const float* wz = (const float*)d_in[3];
    const float* bz = (const float*)d_in[4];
    const float* wh = (const float*)d_in[5];
    const float* bh = (const float*)d_in[6];
    float* out = (float*)d_out;

    const size_t nxt_all = (size_t)BB*TT*NPIX*CIN;   // shorts
    const size_t nh      = (size_t)BB*NPIX*COUT;
    const size_t nwf     = (size_t)3*9*4*4*64*8;
    const size_t nux     = (size_t)3*BB*TT*NPIX*COUT;
    const size_t need    = (nxt_all + 2*nh + nwf + 128 + nux) * sizeof(short);

    if (ws_size >= need) {
        short* xt  = (short*)d_ws;           // [B*T][NPIX][CIN]  bf16
        short* htb = xt  + nxt_all;          // [B][NPIX][COUT]   bf16
        short* rht = htb + nh;               // [B][NPIX][COUT]   bf16
        short* wf  = rht + nh;               // fragments
        short* zp  = wf  + nwf;              // 128 zeros
        short* ux  = zp  + 128;              // [3][B*T][NPIX][COUT] fp16

        convert_w<<<108, 256, 0, stream>>>(wr, wz, wh, wf, zp);
        convert_x_all<<<dim3(NPIX/64, BB*TT), 256, 0, stream>>>(x, xt);
        precompute_ux<<<dim3(NPIX/128, BB*TT, 3), 256, 0, stream>>>(xt, wf, zp, ux);
        for (int t = 0; t < TT; ++t) {
            gates2<<<dim3(NPIX/128, BB, 2), 256, 0, stream>>>(htb, wf, zp, ux, br, bz, out, rht, t);
            cand2 <<<dim3(NPIX/128, BB, 2), 256, 0, stream>>>(rht, wf, zp, ux, bh, out, htb, t);
        }
    } else {
        // fallback: R3 path (~14.6 MB workspace)
        short* xt  = (short*)d_ws;
        short* htb = xt  + (size_t)BB*NPIX*CIN;
        short* rht = htb + nh;
        short* wf  = rht + nh;
        short* zp  = wf  + nwf;
        convert_w<<<108, 256, 0, stream>>>(wr, wz, wh, wf, zp);
        dim3 cxgrid(NPIX/64, BB);
        dim3 ggrid(NPIX/128, BB);
        for (int t = 0; t < TT; ++t) {
            convert_x<<<cxgrid, 256, 0, stream>>>(x, xt, t);
            gates_mfma<<<ggrid, 256, 0, stream>>>(xt, htb, wf, zp, br, bz, out, rht, t);
            cand_mfma <<<ggrid, 256, 0, stream>>>(xt, rht, wf, zp, bh, out, htb, t);
        }
    }
}

// Round 5
// 601.178 us; speedup vs baseline: 52.1410x; 1.1915x over previous
//
#include <hip/hip_runtime.h>
#include <hip/hip_fp16.h>

#define HWD  96
#define NPIX (HWD*HWD)   // 9216
#define CIN  64
#define COUT 64
#define CTOT 128
#define BB   4
#define TT   8
#define WSTR (CTOT*9)    // weight stride per oc in source layout

#define TILE 128         // px per block (sequential kernels)
#define HALO 97
#define SPX  (TILE + 2*HALO)   // 322 staged px
#define LROW 72                // shorts per px row in LDS (64 data + 8 pad)

typedef short bf16x8 __attribute__((ext_vector_type(8)));
typedef float f32x4  __attribute__((ext_vector_type(4)));

__device__ __forceinline__ float sigmoid_(float v){ return 1.0f/(1.0f+__expf(-v)); }
__device__ __forceinline__ float tanh_(float v){
    float e = __expf(2.0f*fabsf(v));
    float t = 1.0f - 2.0f/(e+1.0f);
    return copysignf(t, v);
}
__device__ __forceinline__ short f2bf(float f){      // RNE float->bf16 bits
    unsigned u = __float_as_uint(f);
    u += 0x7fffu + ((u>>16)&1u);
    return (short)(u>>16);
}
__device__ __forceinline__ float b2f(short s){
    return __uint_as_float(((unsigned)(unsigned short)s) << 16);
}
__device__ __forceinline__ short f2h(float f){
    return (short)__half_as_ushort(__float2half(f));
}
__device__ __forceinline__ float h2f(short s){
    return __half2float(__ushort_as_half((unsigned short)s));
}

// ---------------------------------------------------------------------------
// Transpose-convert x: [bt][ic][px] fp32 -> [bt][px][ic] bf16, all timesteps.
// ---------------------------------------------------------------------------
__global__ __launch_bounds__(256) void convert_x_all(const float* __restrict__ x,
                                                     short* __restrict__ xt){
    __shared__ float tile[64][65];
    const int bt  = blockIdx.y;
    const int px0 = blockIdx.x * 64;
    const float* src = x + (size_t)bt*CIN*NPIX;
    short* dst = xt + (size_t)bt*NPIX*CIN;
    const int tid = threadIdx.x;
#pragma unroll
    for (int i = 0; i < 16; ++i){
        int ic = i*4 + (tid>>6);
        int pl = tid & 63;
        tile[ic][pl] = src[(size_t)ic*NPIX + px0 + pl];
    }
    __syncthreads();
#pragma unroll
    for (int i = 0; i < 16; ++i){
        int ic = tid & 63;
        int pl = i*4 + (tid>>6);
        dst[(size_t)(px0+pl)*CIN + ic] = f2bf(tile[ic][pl]);
    }
}

// per-timestep variant (fallback path)
__global__ __launch_bounds__(256) void convert_x(const float* __restrict__ x,
                                                 short* __restrict__ xt, int t){
    __shared__ float tile[64][65];
    const int b   = blockIdx.y;
    const int px0 = blockIdx.x * 64;
    const float* src = x + ((size_t)(b*TT + t)*CIN)*NPIX;
    short* dst = xt + ((size_t)b*NPIX)*CIN;
    const int tid = threadIdx.x;
#pragma unroll
    for (int i = 0; i < 16; ++i){
        int ic = i*4 + (tid>>6);
        int pl = tid & 63;
        tile[ic][pl] = src[(size_t)ic*NPIX + px0 + pl];
    }
    __syncthreads();
#pragma unroll
    for (int i = 0; i < 16; ++i){
        int ic = tid & 63;
        int pl = i*4 + (tid>>6);
        dst[(size_t)(px0+pl)*CIN + ic] = f2bf(tile[ic][pl]);
    }
}

// ---------------------------------------------------------------------------
// Weights -> MFMA A-fragment order: wfrag[c][tap][kc][mt][lane][8],
// element = W_c[oc=mt*16+(lane&15)][ct=kc*32+(lane>>4)*8+j][tap]. Zero pad too.
// ---------------------------------------------------------------------------
__global__ __launch_bounds__(256) void convert_w(const float* __restrict__ wr,
    const float* __restrict__ wz, const float* __restrict__ wh,
    short* __restrict__ wfrag, short* __restrict__ zpad){
    const int g = blockIdx.x*256 + threadIdx.x;      // 0 .. 27647
    if (g < 128) zpad[g] = 0;
    const int lane = g & 63, rest = g >> 6;
    const int mt = rest & 3, kc = (rest>>2)&3, rem = rest>>4;
    const int tap = rem % 9, c = rem / 9;
    const float* wsrc = (c==0) ? wr : (c==1) ? wz : wh;
    const int oc  = mt*16 + (lane&15);
    const int ctb = kc*32 + (lane>>4)*8;
    bf16x8 v;
#pragma unroll
    for (int j=0;j<8;++j)
        v[j] = f2bf(wsrc[(size_t)oc*WSTR + (size_t)(ctb+j)*9 + tap]);
    *(bf16x8*)(wfrag + (size_t)g*8) = v;
}

// ---------------------------------------------------------------------------
// Fused precompute: Ux_c = conv(W_c[:, :64], x_t) for ALL c in one pass.
// Grid (72, B*T, 2=mt-half).  Each B-fragment feeds 12 MFMAs (3c x 2mt x ...).
// ---------------------------------------------------------------------------
__global__ __launch_bounds__(256) void precompute_ux3(
    const short* __restrict__ xt, const short* __restrict__ wfrag,
    const short* __restrict__ zpad, short* __restrict__ ux)
{
    const int lane = threadIdx.x & 63;
    const int wave = threadIdx.x >> 6;
    const int quad = lane >> 4, col = lane & 15;
    const int bt = blockIdx.y, mh = blockIdx.z;
    const int n_base = blockIdx.x*128 + wave*32;

    int px[2], xx[2], yy[2];
#pragma unroll
    for (int nt=0; nt<2; ++nt){
        px[nt] = n_base + nt*16 + col;
        yy[nt] = px[nt]/HWD;
        xx[nt] = px[nt] - yy[nt]*HWD;
    }

    f32x4 acc[3][2][2];
#pragma unroll
    for (int c=0;c<3;++c)
#pragma unroll
    for (int mtl=0;mtl<2;++mtl)
#pragma unroll
    for (int nt=0;nt<2;++nt) acc[c][mtl][nt] = f32x4{0.f,0.f,0.f,0.f};

    const short* xs = xt + (size_t)bt*NPIX*CIN;
    for (int tap=0; tap<9; ++tap){
        const int ky = tap/3, kx = tap-3*ky;
        const int off = (ky-1)*HWD + (kx-1);
        const short* bp[2];
#pragma unroll
        for (int nt=0;nt<2;++nt){
            bool v = ((unsigned)(yy[nt]+ky-1) < HWD) && ((unsigned)(xx[nt]+kx-1) < HWD);
            bp[nt] = v ? (xs + (size_t)(px[nt]+off)*CIN) : zpad;
        }
#pragma unroll
        for (int kcl=0; kcl<2; ++kcl){
            bf16x8 bfr[2];
#pragma unroll
            for (int nt=0;nt<2;++nt)
                bfr[nt] = *(const bf16x8*)(bp[nt] + kcl*32 + quad*8);
#pragma unroll
            for (int c=0;c<3;++c){
                const short* wc = wfrag + (size_t)(((c*9+tap)*4 + kcl)*4)*64*8;
#pragma unroll
                for (int mtl=0;mtl<2;++mtl){
                    const int mt = mh*2 + mtl;
                    bf16x8 a = *(const bf16x8*)(wc + (size_t)(mt*64+lane)*8);
#pragma unroll
                    for (int nt=0;nt<2;++nt)
                        acc[c][mtl][nt] = __builtin_amdgcn_mfma_f32_16x16x32_bf16(
                            a, bfr[nt], acc[c][mtl][nt], 0, 0, 0);
                }
            }
        }
    }

#pragma unroll
    for (int c=0;c<3;++c){
        short* uxs = ux + ((size_t)c*(BB*TT) + bt)*NPIX*COUT;
#pragma unroll
        for (int mtl=0; mtl<2; ++mtl){
            const int ocb = (mh*2+mtl)*16 + quad*4;
#pragma unroll
            for (int nt=0; nt<2; ++nt){
                short4 v;
                v.x = f2h(acc[c][mtl][nt][0]); v.y = f2h(acc[c][mtl][nt][1]);
                v.z = f2h(acc[c][mtl][nt][2]); v.w = f2h(acc[c][mtl][nt][3]);
                *(short4*)(uxs + (size_t)px[nt]*COUT + ocb) = v;
            }
        }
    }
}

// ---------------------------------------------------------------------------
// Gates (sequential, LDS-staged): h-part conv (K=64). blockIdx.z: 0=r, 1=z.
// Block = 512 threads (8 waves x 16 px), tile = 128 px + 97 halo each side.
// ---------------------------------------------------------------------------
__global__ __launch_bounds__(512) void gates3(
    const short* __restrict__ htb, const short* __restrict__ wfrag,
    const short* __restrict__ ux,
    const float* __restrict__ br, const float* __restrict__ bz,
    float* __restrict__ out, short* __restrict__ rht, int t)
{
    __shared__ short hls[SPX*LROW];     // 46.4 KB
    const int tid = threadIdx.x;
    const int lane = tid & 63, wave = tid >> 6;
    const int quad = lane >> 4, col = lane & 15;
    const int b = blockIdx.y, c = blockIdx.z;
    const int p0 = blockIdx.x*TILE;
    const int px = p0 + wave*16 + col;
    const int yy = px/HWD, xx = px - yy*HWD;
    const int lpc = px - (p0 - HALO);   // local center px in LDS

    // stage h neighborhood tile (only when h exists)
    if (t > 0){
        const short* hs = htb + (size_t)b*NPIX*COUT;
        const int p_lo = p0 - HALO;
#pragma unroll
        for (int r = 0; r < 6; ++r){
            int e = r*512 + tid;
            if (e < SPX*8){
                int lp = e >> 3, ck = (e & 7) * 8;
                int gp = min(max(p_lo + lp, 0), NPIX-1);
                *(int4*)&hls[lp*LROW + ck] = *(const int4*)&hs[(size_t)gp*COUT + ck];
            }
        }
    }

    // prologue: Ux load (latency hidden behind staging + K-loop)
    const short* uxs = ux + (((size_t)c*BB + b)*TT + t)*NPIX*COUT;
    short4 uxv[4];
#pragma unroll
    for (int mt=0; mt<4; ++mt)
        uxv[mt] = *(const short4*)(uxs + (size_t)px*COUT + mt*16 + quad*4);

    f32x4 acc[4];
#pragma unroll
    for (int mt=0;mt<4;++mt) acc[mt] = f32x4{0.f,0.f,0.f,0.f};

    if (t > 0){
        __syncthreads();
        const bf16x8 zv = {};
        for (int tap=0; tap<9; ++tap){
            const int ky = tap/3, kx = tap-3*ky;
            const int off = (ky-1)*HWD + (kx-1);
            const bool v = ((unsigned)(yy+ky-1) < HWD) && ((unsigned)(xx+kx-1) < HWD);
            const short* bbase = &hls[(lpc + off)*LROW];
#pragma unroll
            for (int kcl=0; kcl<2; ++kcl){
                bf16x8 bfr = *(const bf16x8*)(bbase + kcl*32 + quad*8);
                bfr = v ? bfr : zv;
                const short* wc = wfrag + (size_t)(((c*9+tap)*4 + 2+kcl)*4)*64*8;
#pragma unroll
                for (int mt=0;mt<4;++mt){
                    bf16x8 a = *(const bf16x8*)(wc + (size_t)(mt*64+lane)*8);
                    acc[mt] = __builtin_amdgcn_mfma_f32_16x16x32_bf16(a, bfr, acc[mt], 0, 0, 0);
                }
            }
        }
    }

    if (c == 0){   // reset gate -> r*h (bf16, [px][oc]); h read from LDS (bf16)
        short* rhs = rht + (size_t)b*NPIX*COUT;
#pragma unroll
        for (int mt=0; mt<4; ++mt){
            const int ocb = mt*16 + quad*4;
            short4 h4 = make_short4(0,0,0,0);
            if (t > 0) h4 = *(const short4*)&hls[lpc*LROW + ocb];
            const short* uq = (const short*)&uxv[mt];
            const short* hq = (const short*)&h4;
            short rh4[4];
#pragma unroll
            for (int reg=0; reg<4; ++reg){
                const int oc = ocb + reg;
                float r = sigmoid_(acc[mt][reg] + h2f(uq[reg]) + br[oc]);
                rh4[reg] = f2bf(r * b2f(hq[reg]));
            }
            *(short4*)(rhs + (size_t)px*COUT + ocb) =
                make_short4(rh4[0], rh4[1], rh4[2], rh4[3]);
        }
    } else {       // update gate -> z (fp32, scratch in out slice t)
        float* zout = out + ((size_t)(b*TT+t)*COUT)*NPIX;
#pragma unroll
        for (int mt=0; mt<4; ++mt){
            const int ocb = mt*16 + quad*4;
            const short* uq = (const short*)&uxv[mt];
#pragma unroll
            for (int reg=0; reg<4; ++reg){
                const int oc = ocb + reg;
                zout[(size_t)oc*NPIX + px] =
                    sigmoid_(acc[mt][reg] + h2f(uq[reg]) + bz[oc]);
            }
        }
    }
}

// ---------------------------------------------------------------------------
// Candidate (sequential, LDS-staged): conv over r*h (K=64) + GRU update.
// blockIdx.z = mh (oc half).  fp32 h recurrence preserved via out slices.
// ---------------------------------------------------------------------------
__global__ __launch_bounds__(512) void cand3(
    const short* __restrict__ rht, const short* __restrict__ wfrag,
    const short* __restrict__ ux, const float* __restrict__ bh,
    float* __restrict__ out, short* __restrict__ htb, int t)
{
    __shared__ short rls[SPX*LROW];     // 46.4 KB
    const int tid = threadIdx.x;
    const int lane = tid & 63, wave = tid >> 6;
    const int quad = lane >> 4, col = lane & 15;
    const int b = blockIdx.y, mh = blockIdx.z;
    const int p0 = blockIdx.x*TILE;
    const int px = p0 + wave*16 + col;
    const int yy = px/HWD, xx = px - yy*HWD;
    const int lpc = px - (p0 - HALO);

    if (t > 0){
        const short* rs = rht + (size_t)b*NPIX*COUT;
        const int p_lo = p0 - HALO;
#pragma unroll
        for (int r = 0; r < 6; ++r){
            int e = r*512 + tid;
            if (e < SPX*8){
                int lp = e >> 3, ck = (e & 7) * 8;
                int gp = min(max(p_lo + lp, 0), NPIX-1);
                *(int4*)&rls[lp*LROW + ck] = *(const int4*)&rs[(size_t)gp*COUT + ck];
            }
        }
    }

    const short* uxs = ux + (((size_t)2*BB + b)*TT + t)*NPIX*COUT;
    short4 uxv[2];
#pragma unroll
    for (int mtl=0; mtl<2; ++mtl)
        uxv[mtl] = *(const short4*)(uxs + (size_t)px*COUT + (mh*2+mtl)*16 + quad*4);

    f32x4 acc[2];
#pragma unroll
    for (int mtl=0;mtl<2;++mtl) acc[mtl] = f32x4{0.f,0.f,0.f,0.f};

    if (t > 0){
        __syncthreads();
        const bf16x8 zv = {};
        for (int tap=0; tap<9; ++tap){
            const int ky = tap/3, kx = tap-3*ky;
            const int off = (ky-1)*HWD + (kx-1);
            const bool v = ((unsigned)(yy+ky-1) < HWD) && ((unsigned)(xx+kx-1) < HWD);
            const short* bbase = &rls[(lpc + off)*LROW];
#pragma unroll
            for (int kcl=0; kcl<2; ++kcl){
                bf16x8 bfr = *(const bf16x8*)(bbase + kcl*32 + quad*8);
                bfr = v ? bfr : zv;
                const short* wc = wfrag + (size_t)(((2*9+tap)*4 + 2+kcl)*4)*64*8;
#pragma unroll
                for (int mtl=0;mtl<2;++mtl){
                    const int mt = mh*2 + mtl;
                    bf16x8 a = *(const bf16x8*)(wc + (size_t)(mt*64+lane)*8);
                    acc[mtl] = __builtin_amdgcn_mfma_f32_16x16x32_bf16(a, bfr, acc[mtl], 0, 0, 0);
                }
            }
        }
    }

    float* o = out + ((size_t)(b*TT+t)*COUT)*NPIX;
    const float* hprev = out + ((size_t)(b*TT+t-1)*COUT)*NPIX;   // deref only if t>0
    short* hts = htb + (size_t)b*NPIX*COUT;
#pragma unroll
    for (int mtl=0; mtl<2; ++mtl){
        const int ocb = (mh*2+mtl)*16 + quad*4;
        const short* uq = (const short*)&uxv[mtl];
        short h4[4];
#pragma unroll
        for (int reg=0; reg<4; ++reg){
            const int oc = ocb + reg;
            float htl = tanh_(acc[mtl][reg] + h2f(uq[reg]) + bh[oc]);
            float z   = o[(size_t)oc*NPIX + px];
            float hv  = (t>0) ? hprev[(size_t)oc*NPIX + px] : 0.0f;
            float hn  = fmaf(z, htl - hv, hv);
            o[(size_t)oc*NPIX + px] = hn;
            h4[reg] = f2bf(hn);
        }
        *(short4*)(hts + (size_t)px*COUT + ocb) =
            make_short4(h4[0], h4[1], h4[2], h4[3]);
    }
}

// ===========================================================================
// Fallback kernels (R3 path, used only if workspace is too small for Ux)
// ===========================================================================
__global__ __launch_bounds__(256) void gates_mfma(
    const short* __restrict__ xt, const short* __restrict__ ht,
    const short* __restrict__ wfrag, const short* __restrict__ zpad,
    const float* __restrict__ br, const float* __restrict__ bz,
    float* __restrict__ out, short* __restrict__ rht, int t)
{
    const int lane = threadIdx.x & 63;
    const int wave = threadIdx.x >> 6;
    const int quad = lane >> 4, col = lane & 15;
    const int b = blockIdx.y;
    const int n_base = blockIdx.x*128 + wave*32;

    int px[2], xx[2], yy[2];
#pragma unroll
    for (int nt=0; nt<2; ++nt){
        px[nt] = n_base + nt*16 + col;
        yy[nt] = px[nt]/HWD;
        xx[nt] = px[nt] - yy[nt]*HWD;
    }
    f32x4 acc[2][4][2];
#pragma unroll
    for(int c=0;c<2;++c)
#pragma unroll
    for(int mt=0;mt<4;++mt)
#pragma unroll
    for(int nt=0;nt<2;++nt) acc[c][mt][nt] = f32x4{0.f,0.f,0.f,0.f};

    const short* xs = xt + ((size_t)b*NPIX)*CIN;
    const short* hs = ht + ((size_t)b*NPIX)*COUT;
    const int nparts = (t>0) ? 2 : 1;
    for (int part=0; part<nparts; ++part){
        const short* src = part ? hs : xs;
        for (int tap=0; tap<9; ++tap){
            const int ky = tap/3, kx = tap-3*ky;
            const int off = (ky-1)*HWD + (kx-1);
            const short* bp[2];
#pragma unroll
            for (int nt=0;nt<2;++nt){
                bool v = ((unsigned)(yy[nt]+ky-1) < HWD) && ((unsigned)(xx[nt]+kx-1) < HWD);
                bp[nt] = v ? (src + (size_t)(px[nt]+off)*CIN) : zpad;
            }
#pragma unroll
            for (int kcl=0; kcl<2; ++kcl){
                const int kc = part*2 + kcl;
                bf16x8 bfr[2];
#pragma unroll
                for (int nt=0;nt<2;++nt)
                    bfr[nt] = *(const bf16x8*)(bp[nt] + kcl*32 + quad*8);
#pragma unroll
                for (int c=0;c<2;++c){
                    const short* wc = wfrag + (size_t)(((c*9+tap)*4 + kc)*4)*64*8;
#pragma unroll
                    for (int mt=0;mt<4;++mt){
                        bf16x8 a = *(const bf16x8*)(wc + (size_t)(mt*64+lane)*8);
#pragma unroll
                        for (int nt=0;nt<2;++nt)
                            acc[c][mt][nt] = __builtin_amdgcn_mfma_f32_16x16x32_bf16(
                                a, bfr[nt], acc[c][mt][nt], 0, 0, 0);
                    }
                }
            }
        }
    }
    float* zout = out + ((size_t)(b*TT+t)*COUT)*NPIX;
    const float* hprev = out + ((size_t)(b*TT+t-1)*COUT)*NPIX;
    short* rhs = rht + ((size_t)b*NPIX)*COUT;
#pragma unroll
    for (int mt=0; mt<4; ++mt){
        const int ocb = mt*16 + quad*4;
#pragma unroll
        for (int nt=0; nt<2; ++nt){
            const int p = px[nt];
            short rh4[4];
#pragma unroll
            for (int reg=0; reg<4; ++reg){
                const int oc = ocb + reg;
                float z = sigmoid_(acc[1][mt][nt][reg] + bz[oc]);
                zout[(size_t)oc*NPIX + p] = z;
                float hv = (t>0) ? hprev[(size_t)oc*NPIX + p] : 0.0f;
                float r  = sigmoid_(acc[0][mt][nt][reg] + br[oc]);
                rh4[reg] = f2bf(r*hv);
            }
            *(short4*)(rhs + (size_t)p*COUT + ocb) =
                make_short4(rh4[0], rh4[1], rh4[2], rh4[3]);
        }
    }
}

__global__ __launch_bounds__(256) void cand_mfma(
    const short* __restrict__ xt, const short* __restrict__ rht,
    const short* __restrict__ wfrag, const short* __restrict__ zpad,
    const float* __restrict__ bh,
    float* __restrict__ out, short* __restrict__ ht, int t)
{
    const int lane = threadIdx.x & 63;
    const int wave = threadIdx.x >> 6;
    const int quad = lane >> 4, col = lane & 15;
    const int b = blockIdx.y;
    const int n_base = blockIdx.x*128 + wave*32;

    int px[2], xx[2], yy[2];
#pragma unroll
    for (int nt=0; nt<2; ++nt){
        px[nt] = n_base + nt*16 + col;
        yy[nt] = px[nt]/HWD;
        xx[nt] = px[nt] - yy[nt]*HWD;
    }
    f32x4 acc[4][2];
#pragma unroll
    for(int mt=0;mt<4;++mt)
#pragma unroll
    for(int nt=0;nt<2;++nt) acc[mt][nt] = f32x4{0.f,0.f,0.f,0.f};

    const short* xs = xt + ((size_t)b*NPIX)*CIN;
    const short* rs = rht + ((size_t)b*NPIX)*COUT;
    const int nparts = (t>0) ? 2 : 1;
    for (int part=0; part<nparts; ++part){
        const short* src = part ? rs : xs;
        for (int tap=0; tap<9; ++tap){
            const int ky = tap/3, kx = tap-3*ky;
            const int off = (ky-1)*HWD + (kx-1);
            const short* bp[2];
#pragma unroll
            for (int nt=0;nt<2;++nt){
                bool v = ((unsigned)(yy[nt]+ky-1) < HWD) && ((unsigned)(xx[nt]+kx-1) < HWD);
                bp[nt] = v ? (src + (size_t)(px[nt]+off)*CIN) : zpad;
            }
#pragma unroll
            for (int kcl=0; kcl<2; ++kcl){
                const int kc = part*2 + kcl;
                bf16x8 bfr[2];
#pragma unroll
                for (int nt=0;nt<2;++nt)
                    bfr[nt] = *(const bf16x8*)(bp[nt] + kcl*32 + quad*8);
                const short* wc = wfrag + (size_t)(((2*9+tap)*4 + kc)*4)*64*8;
#pragma unroll
                for (int mt=0;mt<4;++mt){
                    bf16x8 a = *(const bf16x8*)(wc + (size_t)(mt*64+lane)*8);
#pragma unroll
                    for (int nt=0;nt<2;++nt)
                        acc[mt][nt] = __builtin_amdgcn_mfma_f32_16x16x32_bf16(
                            a, bfr[nt], acc[mt][nt], 0, 0, 0);
                }
            }
        }
    }
    float* o = out + ((size_t)(b*TT+t)*COUT)*NPIX;
    const float* hprev = out + ((size_t)(b*TT+t-1)*COUT)*NPIX;
    short* hts = ht + ((size_t)b*NPIX)*COUT;
#pragma unroll
    for (int mt=0; mt<4; ++mt){
        const int ocb = mt*16 + quad*4;
#pragma unroll
        for (int nt=0; nt<2; ++nt){
            const int p = px[nt];
            short h4[4];
#pragma unroll
            for (int reg=0; reg<4; ++reg){
                const int oc = ocb + reg;
                float htl = tanh_(acc[mt][nt][reg] + bh[oc]);
                float z   = o[(size_t)oc*NPIX + p];
                float hv  = (t>0) ? hprev[(size_t)oc*NPIX + p] : 0.0f;
                float hn  = fmaf(z, htl - hv, hv);
                o[(size_t)oc*NPIX + p] = hn;
                h4[reg] = f2bf(hn);
            }
            *(short4*)(hts + (size_t)p*COUT + ocb) =
                make_short4(h4[0], h4[1], h4[2], h4[3]);
        }
    }
}

extern "C" void kernel_launch(void* const* d_in, const int* in_sizes, int n_in,
                              void* d_out, int out_size, void* d_ws, size_t ws_size,
                              hipStream_t stream) {
    const float* x  = (const float*)d_in[0];
    const float* wr = (const float*)d_in[1];
    const float* br = (const float*)d_in[2];
    const float* wz = (const float*)d_in[3];
    const float* bz = (const float*)d_in[4];
    const float* wh = (const float*)d_in[5];
    const float* bh = (const float*)d_in[6];
    float* out = (float*)d_out;

    const size_t nxt_all = (size_t)BB*TT*NPIX*CIN;   // shorts
    const size_t nh      = (size_t)BB*NPIX*COUT;
    const size_t nwf     = (size_t)3*9*4*4*64*8;
    const size_t nux     = (size_t)3*BB*TT*NPIX*COUT;
    const size_t need    = (nxt_all + 2*nh + nwf + 128 + nux) * sizeof(short);

    if (ws_size >= need) {
        short* xt  = (short*)d_ws;           // [B*T][NPIX][CIN]  bf16
        short* htb = xt  + nxt_all;          // [B][NPIX][COUT]   bf16
        short* rht = htb + nh;               // [B][NPIX][COUT]   bf16
        short* wf  = rht + nh;               // fragments
        short* zp  = wf  + nwf;              // 128 zeros
        short* ux  = zp  + 128;              // [3][B*T][NPIX][COUT] fp16

        convert_w<<<108, 256, 0, stream>>>(wr, wz, wh, wf, zp);
        convert_x_all<<<dim3(NPIX/64, BB*TT), 256, 0, stream>>>(x, xt);
        precompute_ux3<<<dim3(NPIX/128, BB*TT, 2), 256, 0, stream>>>(xt, wf, zp, ux);
        for (int t = 0; t < TT; ++t) {
            gates3<<<dim3(NPIX/TILE, BB, 2), 512, 0, stream>>>(htb, wf, ux, br, bz, out, rht, t);
            cand3 <<<dim3(NPIX/TILE, BB, 2), 512, 0, stream>>>(rht, wf, ux, bh, out, htb, t);
        }
    } else {
        // fallback: R3 path (~14.6 MB workspace)
        short* xt  = (short*)d_ws;
        short* htb = xt  + (size_t)BB*NPIX*CIN;
        short* rht = htb + nh;
        short* wf  = rht + nh;
        short* zp  = wf  + nwf;
        convert_w<<<108, 256, 0, stream>>>(wr, wz, wh, wf, zp);
        dim3 cxgrid(NPIX/64, BB);
        dim3 ggrid(NPIX/128, BB);
        for (int t = 0; t < TT; ++t) {
            convert_x<<<cxgrid, 256, 0, stream>>>(x, xt, t);
            gates_mfma<<<ggrid, 256, 0, stream>>>(xt, htb, wf, zp, br, bz, out, rht, t);
            cand_mfma <<<ggrid, 256, 0, stream>>>(xt, rht, wf, zp, bh, out, htb, t);
        }
    }
}